// Round 8
// baseline (149.069 us; speedup 1.0000x reference)
//
#include <hip/hip_runtime.h>
#include <cmath>

#define C 128     // in/out channels

typedef __bf16 bf16x8 __attribute__((ext_vector_type(8)));
typedef float  f32x4  __attribute__((ext_vector_type(4)));
typedef unsigned short u16x8 __attribute__((ext_vector_type(8)));

// fp32 -> bf16 bits, round-to-nearest-even
static __device__ __forceinline__ unsigned short f2b(float f) {
    unsigned int u = __builtin_bit_cast(unsigned int, f);
    u += 0x7FFFu + ((u >> 16) & 1u);
    return (unsigned short)(u >> 16);
}
// bf16 bits -> fp32
static __device__ __forceinline__ float b2f(unsigned short u) {
    return __builtin_bit_cast(float, (unsigned int)u << 16);
}

// ---------------------------------------------------------------------------
// Zero the counts array (HIP's fill kernel is launch-latency overhead).
// ---------------------------------------------------------------------------
__global__ __launch_bounds__(256)
void sage_zero(int4* __restrict__ p, int n4) {
    int i = blockIdx.x * blockDim.x + threadIdx.x;
    if (i < n4) p[i] = make_int4(0, 0, 0, 0);
}

// ---------------------------------------------------------------------------
// Fused prep kernel, role by block range:
//  [0, CB)          : in-degree counts, 8 edges/thread (int atomics)
//  [CB, CB+XB)      : x fp32 -> bf16, 8 elems/thread
//  [CB+XB, +16)     : pack B = [Wl;Wr] (K=256 x N=128) into MFMA-fragment
//                     order: frag f = t*8+c, lane l, elem j:
//                       k = t*32 + (l>>4)*8 + j, n = c*16 + (l&15)
// ---------------------------------------------------------------------------
__global__ __launch_bounds__(256)
void sage_prep(const int* __restrict__ ei, const float* __restrict__ x,
               const float* __restrict__ Wl, const float* __restrict__ Wr,
               int* __restrict__ counts, unsigned short* __restrict__ xb,
               unsigned short* __restrict__ wp, int E, int CB, int XB) {
    int bid = blockIdx.x;
    int t = threadIdx.x;
    if (bid < CB) {
        int e = (bid * 256 + t) * 8;
        if (e + 7 < E) {
            int4 d0 = *(const int4*)(ei + E + e);
            int4 d1 = *(const int4*)(ei + E + e + 4);
            atomicAdd(&counts[d0.x], 1);
            atomicAdd(&counts[d0.y], 1);
            atomicAdd(&counts[d0.z], 1);
            atomicAdd(&counts[d0.w], 1);
            atomicAdd(&counts[d1.x], 1);
            atomicAdd(&counts[d1.y], 1);
            atomicAdd(&counts[d1.z], 1);
            atomicAdd(&counts[d1.w], 1);
        } else {
            for (; e < E; ++e) atomicAdd(&counts[ei[E + e]], 1);
        }
    } else if (bid < CB + XB) {
        int i = (bid - CB) * 256 + t;        // < N*C/8
        const float4* xp = (const float4*)x + (size_t)i * 2;
        float4 v0 = xp[0];
        float4 v1 = xp[1];
        u16x8 o;
        o[0] = f2b(v0.x); o[1] = f2b(v0.y); o[2] = f2b(v0.z); o[3] = f2b(v0.w);
        o[4] = f2b(v1.x); o[5] = f2b(v1.y); o[6] = f2b(v1.z); o[7] = f2b(v1.w);
        *(u16x8*)(xb + (size_t)i * 8) = o;
    } else {
        int s = (bid - CB - XB) * 256 + t;   // 0..4095
        int f = s >> 6, l = s & 63;
        int tt = f >> 3, c = f & 7;
        int g = l >> 4;
        int n = c * 16 + (l & 15);
        u16x8 o;
#pragma unroll
        for (int j = 0; j < 8; ++j) {
            int k = tt * 32 + g * 8 + j;
            float v = (k < C) ? Wl[(size_t)n * C + k] : Wr[(size_t)n * C + (k - C)];
            o[j] = f2b(v);
        }
        *(u16x8*)(wp + (size_t)s * 8) = o;
    }
}

// ---------------------------------------------------------------------------
// CSR build, step 2: single-block exclusive scan -> cursor.
// After sage_fill, cursor[i] == inclusive scan (end offset of node i).
// ---------------------------------------------------------------------------
__global__ __launch_bounds__(1024)
void sage_scan(const int* __restrict__ counts, int* __restrict__ cursor, int N) {
    __shared__ int part[1024];
    const int t = threadIdx.x;
    const int CH = 64;                    // 1024 * 64 = 65536 >= N
    const int lo = t * CH;

    int s = 0;
    if (lo + CH <= N) {
        const int4* c4 = (const int4*)(counts + lo);
#pragma unroll
        for (int i = 0; i < CH / 4; ++i) {
            int4 v = c4[i];
            s += v.x + v.y + v.z + v.w;
        }
    } else {
        for (int i = lo; i < N; ++i) s += counts[i];
    }
    part[t] = s;
    __syncthreads();
    for (int off = 1; off < 1024; off <<= 1) {
        int v = (t >= off) ? part[t - off] : 0;
        __syncthreads();
        part[t] += v;
        __syncthreads();
    }
    int run = (t == 0) ? 0 : part[t - 1];

    if (lo + CH <= N) {
        const int4* c4 = (const int4*)(counts + lo);
        int4* u4 = (int4*)(cursor + lo);
#pragma unroll
        for (int i = 0; i < CH / 4; ++i) {
            int4 v = c4[i];
            int4 o;
            o.x = run; run += v.x;
            o.y = run; run += v.y;
            o.z = run; run += v.z;
            o.w = run; run += v.w;
            u4[i] = o;
        }
    } else {
        for (int i = lo; i < N; ++i) {
            cursor[i] = run;
            run += counts[i];
        }
    }
}

// ---------------------------------------------------------------------------
// CSR build, step 3: scatter src ids; cursor becomes inclusive scan.
// ---------------------------------------------------------------------------
__global__ __launch_bounds__(256)
void sage_fill(const int* __restrict__ ei, int* __restrict__ cursor,
               int* __restrict__ csr, int E) {
    int i = blockIdx.x * blockDim.x + threadIdx.x;
    int e = i * 4;
    if (e + 3 < E) {
        int4 sv = *(const int4*)(ei + e);
        int4 dv = *(const int4*)(ei + E + e);
        csr[atomicAdd(&cursor[dv.x], 1)] = sv.x;
        csr[atomicAdd(&cursor[dv.y], 1)] = sv.y;
        csr[atomicAdd(&cursor[dv.z], 1)] = sv.z;
        csr[atomicAdd(&cursor[dv.w], 1)] = sv.w;
    } else {
        for (; e < E; ++e) {
            int pos = atomicAdd(&cursor[ei[E + e]], 1);
            csr[pos] = ei[e];
        }
    }
}

// ---------------------------------------------------------------------------
// Fused aggregation + MFMA GEMM + log_softmax.
// Block = 256 thr = 4 waves = 16 nodes.
// Phase 1: wave w aggregates nodes w*4..w*4+3 (quarter-wave per neighbor,
//          4-deep row pipeline) -> bf16 rows in LDS (padded to 136 ushorts:
//          row stride 68 words -> 4-bank rotation on A-frag reads).
// Phase 2: MFMA, K=256 ([agg(LDS) | x(global)]); wave w owns n-tiles
//          {2w,2w+1}; A-frag lane l: node-row l&15, 16B at (t8*4+g)*16.
// Phase 3: +bias -> LDS -> per-node log_softmax within one wave.
// ---------------------------------------------------------------------------
__global__ __launch_bounds__(256)
void sage_agg_mfma_lsm(const unsigned short* __restrict__ xb,
                       const int* __restrict__ cursor,
                       const int* __restrict__ csr,
                       const unsigned short* __restrict__ wp,
                       const float* __restrict__ bias,
                       float* __restrict__ out, int N) {
    __shared__ unsigned short sagg[16][C + 8];   // 8.7 KB
    __shared__ float so[16][132];                // 8.4 KB

    int t = threadIdx.x;
    int w = t >> 6, l = t & 63;
    int base = blockIdx.x * 16;
    int g = l >> 4;          // quarter id
    int fl = l & 15;         // 16B slot within a 256B row

    // ---- Phase 1: aggregate 4 nodes per wave ----
#pragma unroll
    for (int r = 0; r < 4; ++r) {
        int m = w * 4 + r;
        int node = base + m;
        float a[8];
#pragma unroll
        for (int j = 0; j < 8; ++j) a[j] = 0.f;
        int deg = 0;
        if (node < N) {
            int p0 = (node == 0) ? 0 : cursor[node - 1];
            int p1 = cursor[node];
            deg = p1 - p0;
            int p = p0 + g;
            for (; p + 12 < p1; p += 16) {
                int s0 = csr[p];
                int s1 = csr[p + 4];
                int s2 = csr[p + 8];
                int s3 = csr[p + 12];
                u16x8 v0 = *(const u16x8*)(xb + (size_t)s0 * C + fl * 8);
                u16x8 v1 = *(const u16x8*)(xb + (size_t)s1 * C + fl * 8);
                u16x8 v2 = *(const u16x8*)(xb + (size_t)s2 * C + fl * 8);
                u16x8 v3 = *(const u16x8*)(xb + (size_t)s3 * C + fl * 8);
#pragma unroll
                for (int j = 0; j < 8; ++j)
                    a[j] += (b2f(v0[j]) + b2f(v1[j])) + (b2f(v2[j]) + b2f(v3[j]));
            }
            for (; p < p1; p += 4) {
                int s0 = csr[p];
                u16x8 v0 = *(const u16x8*)(xb + (size_t)s0 * C + fl * 8);
#pragma unroll
                for (int j = 0; j < 8; ++j) a[j] += b2f(v0[j]);
            }
        }
#pragma unroll
        for (int j = 0; j < 8; ++j) {
            a[j] += __shfl_xor(a[j], 16);
            a[j] += __shfl_xor(a[j], 32);
        }
        if (g == 0) {
            float inv = 1.0f / fmaxf((float)deg, 1.0f);
            u16x8 o;
#pragma unroll
            for (int j = 0; j < 8; ++j) o[j] = f2b(a[j] * inv);
            *(u16x8*)&sagg[m][fl * 8] = o;
        }
    }
    __syncthreads();

    // ---- Phase 2: MFMA, K = 256 ([agg | x]) ----
    int node = base + (l & 15);
    const bf16x8* Ax = (const bf16x8*)(xb + (size_t)node * C);
    const bf16x8* B  = (const bf16x8*)wp;
    int c0 = w * 2, c1 = w * 2 + 1;
    f32x4 acc0 = {0.f, 0.f, 0.f, 0.f};
    f32x4 acc1 = {0.f, 0.f, 0.f, 0.f};

#pragma unroll
    for (int t8 = 0; t8 < 8; ++t8) {
        bf16x8 a;
        if (t8 < 4) a = *(const bf16x8*)&sagg[l & 15][(t8 * 4 + g) * 8];
        else        a = Ax[(t8 - 4) * 4 + g];
        bf16x8 b0 = B[(size_t)(t8 * 8 + c0) * 64 + l];
        bf16x8 b1 = B[(size_t)(t8 * 8 + c1) * 64 + l];
        acc0 = __builtin_amdgcn_mfma_f32_16x16x32_bf16(a, b0, acc0, 0, 0, 0);
        acc1 = __builtin_amdgcn_mfma_f32_16x16x32_bf16(a, b1, acc1, 0, 0, 0);
    }

    // ---- Phase 3: bias + log_softmax ----
    int fe0 = c0 * 16 + (l & 15);
    int fe1 = c1 * 16 + (l & 15);
    float bb0 = bias[fe0];
    float bb1 = bias[fe1];
#pragma unroll
    for (int r = 0; r < 4; ++r) {
        so[g * 4 + r][fe0] = acc0[r] + bb0;
        so[g * 4 + r][fe1] = acc1[r] + bb1;
    }
    __syncthreads();

#pragma unroll
    for (int i = 0; i < 4; ++i) {
        int nd = w * 4 + i;
        float2 v = *(float2*)&so[nd][l * 2];
        float m = fmaxf(v.x, v.y);
#pragma unroll
        for (int off = 1; off < 64; off <<= 1)
            m = fmaxf(m, __shfl_xor(m, off));
        float s = expf(v.x - m) + expf(v.y - m);
#pragma unroll
        for (int off = 1; off < 64; off <<= 1)
            s += __shfl_xor(s, off);
        float ls = m + logf(s);
        if (base + nd < N) {
            float2 o;
            o.x = v.x - ls;
            o.y = v.y - ls;
            *(float2*)(out + (size_t)(base + nd) * C + l * 2) = o;
        }
    }
}

extern "C" void kernel_launch(void* const* d_in, const int* in_sizes, int n_in,
                              void* d_out, int out_size, void* d_ws, size_t ws_size,
                              hipStream_t stream) {
    const float* x  = (const float*)d_in[0];
    const int*   ei = (const int*)d_in[1];
    const float* Wl = (const float*)d_in[2];
    const float* Wr = (const float*)d_in[3];
    const float* b  = (const float*)d_in[4];
    float* out = (float*)d_out;

    const int N = in_sizes[0] / C;   // 50000
    const int E = in_sizes[1] / 2;   // 600000

    // ws layout (16B-aligned pieces): ~15.8 MB total
    int* counts = (int*)d_ws;                             // N
    int* cursor = counts + N;                             // N
    int* csr    = cursor + N;                             // E
    unsigned short* xb = (unsigned short*)(csr + E);      // N*C bf16
    unsigned short* wp = xb + (size_t)N * C;              // 256*128 bf16 pack

    const int CB = (E + 2047) / 2048;        // count blocks (8 edges/thread)
    const int XB = (N * C / 8) / 256;        // 3125 conv blocks (8 elems/thread)
    int eb4 = (E + 1023) / 1024;
    int n4 = (N + 3) / 4;                    // int4 count for zeroing

    sage_zero<<<(n4 + 255) / 256, 256, 0, stream>>>((int4*)counts, n4);
    sage_prep<<<CB + XB + 16, 256, 0, stream>>>(ei, x, Wl, Wr, counts, xb, wp,
                                                E, CB, XB);
    sage_scan<<<1, 1024, 0, stream>>>(counts, cursor, N);
    sage_fill<<<eb4, 256, 0, stream>>>(ei, cursor, csr, E);
    sage_agg_mfma_lsm<<<(N + 15) / 16, 256, 0, stream>>>(xb, cursor, csr, wp,
                                                         b, out, N);
}